// Round 3
// baseline (345.921 us; speedup 1.0000x reference)
//
#include <hip/hip_runtime.h>

// ---------- helpers ----------
typedef __bf16 bf16x8 __attribute__((ext_vector_type(8)));
typedef float f32x16 __attribute__((ext_vector_type(16)));

__device__ __forceinline__ unsigned short f2bf(float f) {
  unsigned u = __float_as_uint(f);
  u += 0x7FFFu + ((u >> 16) & 1u);   // RNE
  return (unsigned short)(u >> 16);
}

__device__ __forceinline__ void gload_lds16(const void* g, void* l) {
  __builtin_amdgcn_global_load_lds((const __attribute__((address_space(1))) void*)g,
                                   (__attribute__((address_space(3))) void*)l,
                                   16, 0, 0);
}

#define NPTS 4096
#define LDX 576   // padded K for stage-1 phase-1 GEMM
#define GRP 520   // u16 per 8-row x 64-k group (512 data + 8 pad)

// ---------- batched weight transpose+convert: 6 weights in one launch
__global__ __launch_bounds__(256) void convw6_kernel(
    const float* w0, const float* w1, const float* w2,
    const float* r0, const float* r1, const float* r2,
    unsigned short* d0, unsigned short* d1, unsigned short* d2,
    unsigned short* e0, unsigned short* e1, unsigned short* e2) {
  int z = blockIdx.z;
  const float* src; unsigned short* dst; int Ksrc, Kpad, addI;
  switch (z) {
    case 0: src = w0; dst = d0; Ksrc = 524; Kpad = 576; addI = 0; break;
    case 1: src = w1; dst = d1; Ksrc = 513; Kpad = 576; addI = 0; break;
    case 2: src = w2; dst = d2; Ksrc = 513; Kpad = 576; addI = 0; break;
    case 3: src = r0; dst = e0; Ksrc = 512; Kpad = 512; addI = 1; break;
    case 4: src = r1; dst = e1; Ksrc = 512; Kpad = 512; addI = 1; break;
    default: src = r2; dst = e2; Ksrc = 512; Kpad = 512; addI = 1; break;
  }
  int k0 = blockIdx.x * 32;
  if (k0 >= Kpad) return;
  __shared__ float tile[32][33];
  int n0 = blockIdx.y * 32;
  int tx = threadIdx.x & 31, ty = threadIdx.x >> 5;  // 32 x 8
#pragma unroll
  for (int r = 0; r < 32; r += 8) {
    int k = k0 + ty + r, n = n0 + tx;
    tile[ty + r][tx] = (k < Ksrc) ? src[(size_t)k * 512 + n] : 0.f;
  }
  __syncthreads();
#pragma unroll
  for (int r = 0; r < 32; r += 8) {
    int n = n0 + ty + r, k = k0 + tx;
    float v = tile[tx][ty + r];
    if (addI && n == k) v += 1.0f;   // fold residual identity into Wr
    dst[(size_t)n * Kpad + k] = f2bf(v);
  }
}

// ---------- latent fp32 [M][512] -> X bf16 cols 0..511 (row stride LDX)
__global__ __launch_bounds__(256) void conv_latent_kernel(const float* __restrict__ latent,
                                                          unsigned short* __restrict__ X) {
  size_t idx = (size_t)blockIdx.x * 256 + threadIdx.x;  // over M*128 float4 groups
  size_t m = idx >> 7;
  int c4 = (int)(idx & 127) * 4;
  float4 v = *(const float4*)(latent + m * 512 + c4);
  ushort4 o;
  o.x = f2bf(v.x); o.y = f2bf(v.y); o.z = f2bf(v.z); o.w = f2bf(v.w);
  *(ushort4*)(X + m * LDX + c4) = o;
}

// ---------- KNN: nearest non-self neighbor + local covariance -> X cols 512..543
__device__ __forceinline__ void merge1(float& v, int& j, int mk) {
  float ov = __shfl_xor(v, mk); int oj = __shfl_xor(j, mk);
  bool take = (ov > v) || (ov == v && oj < j);   // tie -> lower index (reference top_k)
  v = take ? ov : v; j = take ? oj : j;
}

__global__ __launch_bounds__(512) void knn_kernel(const float* __restrict__ rp,
                                                  unsigned short* __restrict__ X) {
  __shared__ float4 P[NPTS];  // x,y,z,-|p|^2  (64 KB)
  int b = blockIdx.y;
  const float* base = rp + (size_t)b * 3 * NPTS;
  for (int j = threadIdx.x; j < NPTS; j += 512) {
    float x = base[j], y = base[NPTS + j], z = base[2 * NPTS + j];
    float xx = __fadd_rn(__fadd_rn(__fmul_rn(x, x), __fmul_rn(y, y)), __fmul_rn(z, z));
    P[j] = make_float4(x, y, z, -xx);
  }
  __syncthreads();
  int wave = threadIdx.x >> 6, lane = threadIdx.x & 63;
  int grp = lane >> 4, slice = lane & 15;
  int il0 = wave * 8 + grp * 2;          // this lane's two points: il0, il0+1
  int ia = blockIdx.x * 64 + il0;
  int ib = ia + 1;
  float4 pa = P[ia], pb = P[ib];
  float ax = 2.f * pa.x, ay = 2.f * pa.y, az = 2.f * pa.z;
  float bx = 2.f * pb.x, by = 2.f * pb.y, bz = 2.f * pb.z;
  float va = -3.4e38f, vb = -3.4e38f;
  int ta = 0, tb = 0;
  int sta = ((ia & 15) == slice) ? (ia >> 4) : -1;   // self-iteration to poison
  int stb = ((ib & 15) == slice) ? (ib >> 4) : -1;
  const float4* pp = P + slice;
#pragma unroll 8
  for (int t = 0; t < NPTS / 16; ++t) {
    float4 pj = pp[t * 16];
    float ea = __builtin_fmaf(ax, pj.x, __builtin_fmaf(ay, pj.y,
               __builtin_fmaf(az, pj.z, pj.w)));
    float eb = __builtin_fmaf(bx, pj.x, __builtin_fmaf(by, pj.y,
               __builtin_fmaf(bz, pj.z, pj.w)));
    ea = (t == sta) ? -3.4e38f : ea;
    eb = (t == stb) ? -3.4e38f : eb;
    bool ca = ea > va; va = ca ? ea : va; ta = ca ? t : ta;
    bool cb = eb > vb; vb = cb ? eb : vb; tb = cb ? t : tb;
  }
  int ja = ta * 16 + slice, jb = tb * 16 + slice;
#pragma unroll
  for (int mk = 1; mk <= 8; mk <<= 1) {
    merge1(va, ja, mk);
    merge1(vb, jb, mk);
  }
  if (slice == 0) {
#pragma unroll
    for (int p = 0; p < 2; ++p) {
      float4 pi = (p == 0) ? pa : pb;
      float4 p1 = P[(p == 0) ? ja : jb];   // nearest non-self neighbor
      size_t row = (size_t)b * NPTS + ia + p;
      unsigned short* xp = X + row * LDX + 512;
      float vals[12] = { pi.x, pi.y, pi.z,
                         pi.x * p1.x, pi.x * p1.y, pi.x * p1.z,
                         pi.y * p1.x, pi.y * p1.y, pi.y * p1.z,
                         pi.z * p1.x, pi.z * p1.y, pi.z * p1.z };
#pragma unroll
      for (int k = 0; k < 12; ++k) xp[k] = f2bf(vals[k]);
#pragma unroll
      for (int k = 12; k < 32; ++k) xp[k] = 0;   // cols 524..543 (zero weights there)
    }
  }
}

// ---------- FUSED stage kernel: one block = 64 rows, full 512-col hidden in LDS.
// Phase 1: H = relu(X@W1t + b1 [+ std*w1row])  -> LDS (swizzled group layout)
// Phase 2: O = relu(H@(Wr+I)t + br); so[row] += O . w2  (atomic)
// 8 waves, wave w owns output cols [64w,64w+64) in BOTH phases -> its 8 B-groups
// are wave-private: B staging needs no barriers / no dbuf (read frags to regs,
// lgkmcnt(0), restage same region for next K-step). Only A (phase 1) uses a
// 2-buffer + barrier. Phase 2 K-loop is barrier-free (H is read-only).
// LDS: H 64*GRP + B 64*GRP + A 2*8*GRP = 144*GRP u16 = 149,760 B (1 block/CU).
__global__ __launch_bounds__(512) void fused_stage_kernel(
    const unsigned short* __restrict__ Xb, const unsigned short* __restrict__ W1t,
    const float* __restrict__ b1v, const unsigned short* __restrict__ Wrt,
    const float* __restrict__ brv, const float* __restrict__ w2v,
    float* __restrict__ so, int K1,
    const float* __restrict__ stdv, const float* __restrict__ w1row) {
  extern __shared__ unsigned short S[];
  unsigned short* HL = S;                 // 64 groups (8 ktiles x 8 rowgrps)
  unsigned short* BL = S + 64 * GRP;      // 64 groups, [8w,8w+8) private to wave w
  unsigned short* AL = S + 128 * GRP;     // 2 x 8 groups (A dbuf)
  const int t = threadIdx.x;
  const int wave = t >> 6, lane = t & 63;
  const int m0 = blockIdx.x * 64;
  const int srow = lane >> 3;             // staging row within group (0..7)
  const int sslot = (lane & 7) ^ srow;    // permuted k-chunk this lane fetches
  const int l31 = lane & 31, hi = lane >> 5;
  const int w7 = l31 & 7, g2 = l31 >> 3;

  const unsigned short* Arow  = Xb  + (size_t)(m0 + wave * 8 + srow) * LDX + sslot * 8;
  const unsigned short* Wrow1 = W1t + (size_t)(64 * wave + srow) * LDX + sslot * 8;
  const unsigned short* Wrow2 = Wrt + (size_t)(64 * wave + srow) * 512 + sslot * 8;

  auto STAGE_A = [&](int buf, int kt) {
    gload_lds16(Arow + (size_t)kt * 64, AL + buf * (8 * GRP) + wave * GRP);
  };
  auto STAGE_B1 = [&](int kt) {
#pragma unroll
    for (int r = 0; r < 8; ++r)
      gload_lds16(Wrow1 + (size_t)r * 8 * LDX + (size_t)kt * 64, BL + (8 * wave + r) * GRP);
  };
  auto STAGE_B2 = [&](int kt) {
#pragma unroll
    for (int r = 0; r < 8; ++r)
      gload_lds16(Wrow2 + (size_t)r * 8 * 512 + (size_t)kt * 64, BL + (8 * wave + r) * GRP);
  };

  // ---------------- phase 1 ----------------
  STAGE_A(0, 0);
  STAGE_B1(0);
  asm volatile("s_waitcnt vmcnt(0)" ::: "memory");
  __builtin_amdgcn_s_barrier();

  f32x16 acc[2][2] = {};
  const int nt1 = K1 / 64;
  for (int t1 = 0; t1 < nt1; ++t1) {
    const int cur = t1 & 1;
    bf16x8 af[2][4], bf[2][4];
#pragma unroll
    for (int i = 0; i < 2; ++i)
#pragma unroll
      for (int ks = 0; ks < 4; ++ks)
        af[i][ks] = *(const bf16x8*)(AL + cur * (8 * GRP) + (i * 4 + g2) * GRP +
                                     w7 * 64 + (((2 * ks + hi) ^ w7) * 8));
#pragma unroll
    for (int j = 0; j < 2; ++j)
#pragma unroll
      for (int ks = 0; ks < 4; ++ks)
        bf[j][ks] = *(const bf16x8*)(BL + (8 * wave + j * 4 + g2) * GRP +
                                     w7 * 64 + (((2 * ks + hi) ^ w7) * 8));
    asm volatile("s_waitcnt lgkmcnt(0)" ::: "memory");
    __builtin_amdgcn_sched_barrier(0);
    if (t1 + 1 < nt1) {            // restage own B region + next A buf (reads done)
      STAGE_A(cur ^ 1, t1 + 1);
      STAGE_B1(t1 + 1);
    } else {
      STAGE_B2(0);                 // prefetch phase-2 first Wr tile
    }
#pragma unroll
    for (int ks = 0; ks < 4; ++ks)
#pragma unroll
      for (int i = 0; i < 2; ++i)
#pragma unroll
        for (int j = 0; j < 2; ++j)
          acc[i][j] = __builtin_amdgcn_mfma_f32_32x32x16_bf16(af[i][ks], bf[j][ks],
                                                              acc[i][j], 0, 0, 0);
    asm volatile("s_waitcnt vmcnt(0)" ::: "memory");
    __builtin_amdgcn_sched_barrier(0);
    __builtin_amdgcn_s_barrier();
  }

  // rank-1 std fold (stages 2/3): acc += std[row] * w1row[col], exact in f32
  if (w1row) {
    float wv1[2];
#pragma unroll
    for (int j = 0; j < 2; ++j) wv1[j] = w1row[64 * wave + j * 32 + l31];
#pragma unroll
    for (int i = 0; i < 2; ++i)
#pragma unroll
      for (int rg = 0; rg < 16; ++rg) {
        int row = i * 32 + (rg & 3) + 8 * (rg >> 2) + 4 * hi;
        float sv = stdv[m0 + row];
#pragma unroll
        for (int j = 0; j < 2; ++j) acc[i][j][rg] += sv * wv1[j];
      }
  }

  // bias + relu + write H into LDS (swizzled group layout; wave w -> ktile w)
  {
    float bv1[2];
#pragma unroll
    for (int j = 0; j < 2; ++j) bv1[j] = b1v[64 * wave + j * 32 + l31];
#pragma unroll
    for (int i = 0; i < 2; ++i)
#pragma unroll
      for (int j = 0; j < 2; ++j)
#pragma unroll
        for (int rg = 0; rg < 16; ++rg) {
          int r7 = (rg & 3) + 4 * hi;       // row & 7
          int g  = i * 4 + (rg >> 2);       // row >> 3
          int c8 = j * 4 + g2;              // (col>>3)&7
          float v = acc[i][j][rg] + bv1[j];
          v = v > 0.f ? v : 0.f;
          HL[(wave * 8 + g) * GRP + (r7 * 8 + (c8 ^ r7)) * 8 + w7] = f2bf(v);
        }
  }
  asm volatile("s_waitcnt lgkmcnt(0)" ::: "memory");
  __builtin_amdgcn_s_barrier();            // H complete & visible; Wr(0) already landed

  // ---------------- phase 2 (barrier-free K-loop) ----------------
  f32x16 acc2[2][2] = {};
  for (int t2 = 0; t2 < 8; ++t2) {
    bf16x8 af[2][4], bf[2][4];
#pragma unroll
    for (int i = 0; i < 2; ++i)
#pragma unroll
      for (int ks = 0; ks < 4; ++ks)
        af[i][ks] = *(const bf16x8*)(HL + (t2 * 8 + i * 4 + g2) * GRP +
                                     w7 * 64 + (((2 * ks + hi) ^ w7) * 8));
#pragma unroll
    for (int j = 0; j < 2; ++j)
#pragma unroll
      for (int ks = 0; ks < 4; ++ks)
        bf[j][ks] = *(const bf16x8*)(BL + (8 * wave + j * 4 + g2) * GRP +
                                     w7 * 64 + (((2 * ks + hi) ^ w7) * 8));
    asm volatile("s_waitcnt lgkmcnt(0)" ::: "memory");
    __builtin_amdgcn_sched_barrier(0);
    if (t2 < 7) STAGE_B2(t2 + 1);          // wave-private restage
#pragma unroll
    for (int ks = 0; ks < 4; ++ks)
#pragma unroll
      for (int i = 0; i < 2; ++i)
#pragma unroll
        for (int j = 0; j < 2; ++j)
          acc2[i][j] = __builtin_amdgcn_mfma_f32_32x32x16_bf16(af[i][ks], bf[j][ks],
                                                               acc2[i][j], 0, 0, 0);
    if (t2 < 7) {
      asm volatile("s_waitcnt vmcnt(0)" ::: "memory");
      __builtin_amdgcn_sched_barrier(0);
    }
  }

  // epilogue 2: relu(acc2 + br) . w2 -> shfl-reduce over 64 cols -> atomicAdd
  {
    float bv2[2], wv2[2];
#pragma unroll
    for (int j = 0; j < 2; ++j) {
      int col = 64 * wave + j * 32 + l31;
      bv2[j] = brv[col]; wv2[j] = w2v[col];
    }
#pragma unroll
    for (int i = 0; i < 2; ++i)
#pragma unroll
      for (int rg = 0; rg < 16; ++rg) {
        float s = 0.f;
#pragma unroll
        for (int j = 0; j < 2; ++j) {
          float v = acc2[i][j][rg] + bv2[j];   // residual folded into Wr+I
          v = v > 0.f ? v : 0.f;
          s += v * wv2[j];
        }
        s += __shfl_xor(s, 1); s += __shfl_xor(s, 2); s += __shfl_xor(s, 4);
        s += __shfl_xor(s, 8); s += __shfl_xor(s, 16);
        if (l31 == 0) {
          int row = i * 32 + (rg & 3) + 8 * (rg >> 2) + 4 * hi;
          atomicAdd(&so[m0 + row], s);
        }
      }
  }
}

// ---------- small kernels ----------
__global__ __launch_bounds__(256) void init_so_kernel(float* so, const float* b2) {
  int m = blockIdx.x * 256 + threadIdx.x;
  so[m] = b2[0];
}
__global__ __launch_bounds__(256) void update_kernel(float* std_cum, float* so,
                                                     const float* b2_next, int first) {
  int m = blockIdx.x * 256 + threadIdx.x;
  float s = so[m];
  if (!first) s += std_cum[m];
  std_cum[m] = s;
  so[m] = b2_next[0];
}
__global__ __launch_bounds__(256) void finalize_kernel(float* out, const float* std_cum,
                                                       const float* so) {
  int m = blockIdx.x * 256 + threadIdx.x;
  out[m] = std_cum[m] + so[m];
}

extern "C" void kernel_launch(void* const* d_in, const int* in_sizes, int n_in,
                              void* d_out, int out_size, void* d_ws, size_t ws_size,
                              hipStream_t stream) {
  const int B = 8, N = NPTS, M = B * N;
  const float* latent = (const float*)d_in[0];
  const float* rp = (const float*)d_in[1];
  const float* w1[3] = {(const float*)d_in[2], (const float*)d_in[8], (const float*)d_in[14]};
  const float* b1[3] = {(const float*)d_in[3], (const float*)d_in[9], (const float*)d_in[15]};
  const float* wr[3] = {(const float*)d_in[4], (const float*)d_in[10], (const float*)d_in[16]};
  const float* br[3] = {(const float*)d_in[5], (const float*)d_in[11], (const float*)d_in[17]};
  const float* w2[3] = {(const float*)d_in[6], (const float*)d_in[12], (const float*)d_in[18]};
  const float* b2[3] = {(const float*)d_in[7], (const float*)d_in[13], (const float*)d_in[19]};

  char* ws = (char*)d_ws;
  auto carve = [&](size_t bytes) {
    char* p = ws;
    ws += (bytes + 255) & ~(size_t)255;
    return p;
  };
  unsigned short* X = (unsigned short*)carve((size_t)M * LDX * 2);
  unsigned short* W1t[3], *Wrt[3];
  for (int s = 0; s < 3; ++s) W1t[s] = (unsigned short*)carve((size_t)512 * LDX * 2);
  for (int s = 0; s < 3; ++s) Wrt[s] = (unsigned short*)carve((size_t)512 * 512 * 2);
  float* std_cum = (float*)carve((size_t)M * 4);
  float* so      = (float*)carve((size_t)M * 4);

  const size_t ldsBytes = (size_t)144 * GRP * 2;   // 149,760 B

  convw6_kernel<<<dim3(LDX / 32, 16, 6), 256, 0, stream>>>(
      w1[0], w1[1], w1[2], wr[0], wr[1], wr[2],
      W1t[0], W1t[1], W1t[2], Wrt[0], Wrt[1], Wrt[2]);
  conv_latent_kernel<<<(M * 128) / 256, 256, 0, stream>>>(latent, X);
  knn_kernel<<<dim3(N / 64, B), 512, 0, stream>>>(rp, X);
  init_so_kernel<<<M / 256, 256, 0, stream>>>(so, b2[0]);

  for (int s = 0; s < 3; ++s) {
    if (s == 0) {
      fused_stage_kernel<<<dim3(M / 64), 512, ldsBytes, stream>>>(
          X, W1t[s], b1[s], Wrt[s], br[s], w2[s], so, LDX, nullptr, nullptr);
    } else {
      fused_stage_kernel<<<dim3(M / 64), 512, ldsBytes, stream>>>(
          X, W1t[s], b1[s], Wrt[s], br[s], w2[s], so, 512, std_cum,
          w1[s] + (size_t)512 * 512);
    }
    if (s < 2)
      update_kernel<<<M / 256, 256, 0, stream>>>(std_cum, so, b2[s + 1], s == 0 ? 1 : 0);
  }
  finalize_kernel<<<M / 256, 256, 0, stream>>>((float*)d_out, std_cum, so);
}

// Round 4
// 341.615 us; speedup vs baseline: 1.0126x; 1.0126x over previous
//
#include <hip/hip_runtime.h>

// ---------- helpers ----------
typedef __bf16 bf16x8 __attribute__((ext_vector_type(8)));
typedef float f32x16 __attribute__((ext_vector_type(16)));

__device__ __forceinline__ unsigned short f2bf(float f) {
  unsigned u = __float_as_uint(f);
  u += 0x7FFFu + ((u >> 16) & 1u);   // RNE
  return (unsigned short)(u >> 16);
}

__device__ __forceinline__ void gload_lds16(const void* g, void* l) {
  __builtin_amdgcn_global_load_lds((const __attribute__((address_space(1))) void*)g,
                                   (__attribute__((address_space(3))) void*)l,
                                   16, 0, 0);
}

#define NPTS 4096
#define LDX 576   // padded K for stage-1 GEMM1, divisible by BK=64

// ---------- batched weight transpose+convert: 6 weights in one launch
__global__ __launch_bounds__(256) void convw6_kernel(
    const float* w0, const float* w1, const float* w2,
    const float* r0, const float* r1, const float* r2,
    unsigned short* d0, unsigned short* d1, unsigned short* d2,
    unsigned short* e0, unsigned short* e1, unsigned short* e2) {
  int z = blockIdx.z;
  const float* src; unsigned short* dst; int Ksrc, Kpad, addI;
  switch (z) {
    case 0: src = w0; dst = d0; Ksrc = 524; Kpad = 576; addI = 0; break;
    case 1: src = w1; dst = d1; Ksrc = 513; Kpad = 576; addI = 0; break;
    case 2: src = w2; dst = d2; Ksrc = 513; Kpad = 576; addI = 0; break;
    case 3: src = r0; dst = e0; Ksrc = 512; Kpad = 512; addI = 1; break;
    case 4: src = r1; dst = e1; Ksrc = 512; Kpad = 512; addI = 1; break;
    default: src = r2; dst = e2; Ksrc = 512; Kpad = 512; addI = 1; break;
  }
  int k0 = blockIdx.x * 32;
  if (k0 >= Kpad) return;
  __shared__ float tile[32][33];
  int n0 = blockIdx.y * 32;
  int tx = threadIdx.x & 31, ty = threadIdx.x >> 5;  // 32 x 8
#pragma unroll
  for (int r = 0; r < 32; r += 8) {
    int k = k0 + ty + r, n = n0 + tx;
    tile[ty + r][tx] = (k < Ksrc) ? src[(size_t)k * 512 + n] : 0.f;
  }
  __syncthreads();
#pragma unroll
  for (int r = 0; r < 32; r += 8) {
    int n = n0 + ty + r, k = k0 + tx;
    float v = tile[tx][ty + r];
    if (addI && n == k) v += 1.0f;   // fold residual identity into Wr
    dst[(size_t)n * Kpad + k] = f2bf(v);
  }
}

// ---------- latent fp32 [M][512] -> X bf16 cols 0..511 (row stride LDX)
__global__ __launch_bounds__(256) void conv_latent_kernel(const float* __restrict__ latent,
                                                          unsigned short* __restrict__ X) {
  size_t idx = (size_t)blockIdx.x * 256 + threadIdx.x;  // over M*128 float4 groups
  size_t m = idx >> 7;
  int c4 = (int)(idx & 127) * 4;
  float4 v = *(const float4*)(latent + m * 512 + c4);
  ushort4 o;
  o.x = f2bf(v.x); o.y = f2bf(v.y); o.z = f2bf(v.z); o.w = f2bf(v.w);
  *(ushort4*)(X + m * LDX + c4) = o;
}

// ---------- KNN: nearest non-self neighbor + local covariance -> X cols 512..543
__device__ __forceinline__ void merge1(float& v, int& j, int mk) {
  float ov = __shfl_xor(v, mk); int oj = __shfl_xor(j, mk);
  bool take = (ov > v) || (ov == v && oj < j);   // tie -> lower index (reference top_k)
  v = take ? ov : v; j = take ? oj : j;
}

__global__ __launch_bounds__(512) void knn_kernel(const float* __restrict__ rp,
                                                  unsigned short* __restrict__ X) {
  __shared__ float4 P[NPTS];  // x,y,z,-|p|^2  (64 KB)
  int b = blockIdx.y;
  const float* base = rp + (size_t)b * 3 * NPTS;
  for (int j = threadIdx.x; j < NPTS; j += 512) {
    float x = base[j], y = base[NPTS + j], z = base[2 * NPTS + j];
    float xx = __fadd_rn(__fadd_rn(__fmul_rn(x, x), __fmul_rn(y, y)), __fmul_rn(z, z));
    P[j] = make_float4(x, y, z, -xx);
  }
  __syncthreads();
  int wave = threadIdx.x >> 6, lane = threadIdx.x & 63;
  int grp = lane >> 4, slice = lane & 15;
  int il0 = wave * 8 + grp * 2;          // this lane's two points: il0, il0+1
  int ia = blockIdx.x * 64 + il0;
  int ib = ia + 1;
  float4 pa = P[ia], pb = P[ib];
  float ax = 2.f * pa.x, ay = 2.f * pa.y, az = 2.f * pa.z;
  float bx = 2.f * pb.x, by = 2.f * pb.y, bz = 2.f * pb.z;
  float va = -3.4e38f, vb = -3.4e38f;
  int ta = 0, tb = 0;
  int sta = ((ia & 15) == slice) ? (ia >> 4) : -1;   // self-iteration to poison
  int stb = ((ib & 15) == slice) ? (ib >> 4) : -1;
  const float4* pp = P + slice;
#pragma unroll 8
  for (int t = 0; t < NPTS / 16; ++t) {
    float4 pj = pp[t * 16];
    float ea = __builtin_fmaf(ax, pj.x, __builtin_fmaf(ay, pj.y,
               __builtin_fmaf(az, pj.z, pj.w)));
    float eb = __builtin_fmaf(bx, pj.x, __builtin_fmaf(by, pj.y,
               __builtin_fmaf(bz, pj.z, pj.w)));
    ea = (t == sta) ? -3.4e38f : ea;
    eb = (t == stb) ? -3.4e38f : eb;
    bool ca = ea > va; va = ca ? ea : va; ta = ca ? t : ta;
    bool cb = eb > vb; vb = cb ? eb : vb; tb = cb ? t : tb;
  }
  int ja = ta * 16 + slice, jb = tb * 16 + slice;
#pragma unroll
  for (int mk = 1; mk <= 8; mk <<= 1) {
    merge1(va, ja, mk);
    merge1(vb, jb, mk);
  }
  if (slice == 0) {
#pragma unroll
    for (int p = 0; p < 2; ++p) {
      float4 pi = (p == 0) ? pa : pb;
      float4 p1 = P[(p == 0) ? ja : jb];   // nearest non-self neighbor
      size_t row = (size_t)b * NPTS + ia + p;
      unsigned short* xp = X + row * LDX + 512;
      float vals[12] = { pi.x, pi.y, pi.z,
                         pi.x * p1.x, pi.x * p1.y, pi.x * p1.z,
                         pi.y * p1.x, pi.y * p1.y, pi.y * p1.z,
                         pi.z * p1.x, pi.z * p1.y, pi.z * p1.z };
#pragma unroll
      for (int k = 0; k < 12; ++k) xp[k] = f2bf(vals[k]);
#pragma unroll
      for (int k = 12; k < 32; ++k) xp[k] = 0;   // cols 524..543 (zero weights there)
    }
  }
}

// ---------- GEMMs: BM=256 x BN=256, dbuf LDS, 4-phase-per-K-tile schedule (T3+T4+T5):
// phase = one 16-wide k-slice: {6 ds_read frags | stage-issue next tile (A@ks0, B@ks1)
//  | s_barrier | lgkmcnt(0) | setprio(1) 8xMFMA setprio(0) | s_barrier}.
// vmcnt(0) ONLY at tile boundary — next-tile loads issued in ph0/1 get ph2/3 of cover.
// Layout/fragment math byte-identical to the round-2 (proven) kernel.
#define BM 256
#define BN 256
#define BK 64
#define GRP 520   // u16 per 8-row group (512 data + 8 pad)
#define MBLK 128  // M / BM
#define LDSU16 (2 * 64 * GRP)   // 2 buffers x (32 A-groups + 32 B-groups)

__global__ __launch_bounds__(512) void gemm_relu_kernel(
    const unsigned short* __restrict__ Xb, const unsigned short* __restrict__ Wt,
    const float* __restrict__ bias, unsigned short* __restrict__ H,
    int K, int ldx, int ldw,
    const float* __restrict__ stdv, const float* __restrict__ w1row) {
  extern __shared__ unsigned short S[];   // [2][64*GRP]
  const int t = threadIdx.x;
  const int wave = t >> 6, lane = t & 63;
  const int flat = blockIdx.y * gridDim.x + blockIdx.x;
  const int m0 = (flat & (MBLK - 1)) * BM;   // co-panel blocks (f, f+128): same XCD
  const int n0 = (flat >> 7) * BN;
  const int wm = (wave >> 1) * 64;           // 4 m-waves
  const int wn = (wave & 1) * 128;           // 2 n-waves
  const int srow = lane >> 3;                // staging row within group (0..7)
  const int sslot = (lane & 7) ^ srow;       // permuted k-chunk this lane fetches
  const int l31 = lane & 31, hi = lane >> 5;
  const int w7 = l31 & 7, g2 = l31 >> 3;
  const unsigned short* Arow = Xb + (size_t)(m0 + srow) * ldx + sslot * 8;
  const unsigned short* Brow = Wt + (size_t)(n0 + srow) * ldw + sslot * 8;
  f32x16 acc[2][4] = {};
  const int nt = K / BK;
  auto STAGE_A = [&](int buf, int kt) {
#pragma unroll
    for (int r = 0; r < 4; ++r) {
      int g = wave + r * 8;                  // A groups 0..31
      gload_lds16(Arow + (size_t)g * 8 * ldx + kt, S + buf * (64 * GRP) + g * GRP);
    }
  };
  auto STAGE_B = [&](int buf, int kt) {
#pragma unroll
    for (int r = 0; r < 4; ++r) {
      int g = wave + r * 8;                  // B groups 0..31
      gload_lds16(Brow + (size_t)g * 8 * ldw + kt, S + buf * (64 * GRP) + (32 + g) * GRP);
    }
  };
  STAGE_A(0, 0);
  STAGE_B(0, 0);
  asm volatile("s_waitcnt vmcnt(0)" ::: "memory");
  __builtin_amdgcn_s_barrier();
  for (int tt = 0; tt < nt; ++tt) {
    const int cur = tt & 1;
    const unsigned short* Sa = S + cur * (64 * GRP);
    const unsigned short* Sb = Sa + 32 * GRP;
    const bool pf = (tt + 1 < nt);
#pragma unroll
    for (int ks = 0; ks < 4; ++ks) {
      int qx = (ks * 2 + hi) ^ w7;
      bf16x8 a[2], bb[4];
#pragma unroll
      for (int i = 0; i < 2; ++i)
        a[i] = *(const bf16x8*)(Sa + ((wm >> 3) + i * 4 + g2) * GRP + w7 * 64 + qx * 8);
#pragma unroll
      for (int j = 0; j < 4; ++j)
        bb[j] = *(const bf16x8*)(Sb + ((wn >> 3) + j * 4 + g2) * GRP + w7 * 64 + qx * 8);
      if (pf && ks == 0) STAGE_A(cur ^ 1, (tt + 1) * BK);
      if (pf && ks == 1) STAGE_B(cur ^ 1, (tt + 1) * BK);
      __builtin_amdgcn_s_barrier();
      asm volatile("s_waitcnt lgkmcnt(0)" ::: "memory");
      __builtin_amdgcn_sched_barrier(0);           // rule #18: pin MFMA after the wait
      __builtin_amdgcn_s_setprio(1);
#pragma unroll
      for (int i = 0; i < 2; ++i)
#pragma unroll
        for (int j = 0; j < 4; ++j)
          acc[i][j] = __builtin_amdgcn_mfma_f32_32x32x16_bf16(a[i], bb[j], acc[i][j], 0, 0, 0);
      __builtin_amdgcn_s_setprio(0);
      __builtin_amdgcn_sched_barrier(0);
      if (ks < 3) __builtin_amdgcn_s_barrier();
    }
    if (pf) asm volatile("s_waitcnt vmcnt(0)" ::: "memory");   // next tile fully landed
    __builtin_amdgcn_s_barrier();
    asm volatile("" ::: "memory");
  }
  // rank-1 std fold (stages 2/3): acc += std[row] * w1row[col], in f32
  if (w1row) {
    float wv[4];
#pragma unroll
    for (int j = 0; j < 4; ++j) wv[j] = w1row[n0 + wn + j * 32 + l31];
#pragma unroll
    for (int i = 0; i < 2; ++i) {
#pragma unroll
      for (int rg = 0; rg < 16; ++rg) {
        int row = m0 + wm + i * 32 + (rg & 3) + 8 * (rg >> 2) + 4 * hi;
        float sv = stdv[row];
#pragma unroll
        for (int j = 0; j < 4; ++j) acc[i][j][rg] += sv * wv[j];
      }
    }
  }
  // epilogue: C/D layout col=lane&31, row=(reg&3)+8*(reg>>2)+4*(lane>>5)  [m74/m101]
#pragma unroll
  for (int j = 0; j < 4; ++j) {
    int col = n0 + wn + j * 32 + l31;
    float bv = bias[col];
#pragma unroll
    for (int i = 0; i < 2; ++i) {
#pragma unroll
      for (int rg = 0; rg < 16; ++rg) {
        int row = m0 + wm + i * 32 + (rg & 3) + 8 * (rg >> 2) + 4 * hi;
        float v = acc[i][j][rg] + bv;
        v = v > 0.f ? v : 0.f;
        H[(size_t)row * 512 + col] = f2bf(v);
      }
    }
  }
}

// ---------- GEMM2: h2 = relu(H1 @ (Wr+I) + br); stage_out[row] += h2 . w2  (atomic)
__global__ __launch_bounds__(512) void gemm_res_kernel(
    const unsigned short* __restrict__ H1, const unsigned short* __restrict__ Wt,
    const float* __restrict__ br, const float* __restrict__ w2,
    float* __restrict__ so) {
  extern __shared__ unsigned short S[];
  const int t = threadIdx.x;
  const int wave = t >> 6, lane = t & 63;
  const int flat = blockIdx.y * gridDim.x + blockIdx.x;
  const int m0 = (flat & (MBLK - 1)) * BM;
  const int n0 = (flat >> 7) * BN;
  const int wm = (wave >> 1) * 64;
  const int wn = (wave & 1) * 128;
  const int srow = lane >> 3;
  const int sslot = (lane & 7) ^ srow;
  const int l31 = lane & 31, hi = lane >> 5;
  const int w7 = l31 & 7, g2 = l31 >> 3;
  const unsigned short* Arow = H1 + (size_t)(m0 + srow) * 512 + sslot * 8;
  const unsigned short* Brow = Wt + (size_t)(n0 + srow) * 512 + sslot * 8;
  f32x16 acc[2][4] = {};
  auto STAGE_A = [&](int buf, int kt) {
#pragma unroll
    for (int r = 0; r < 4; ++r) {
      int g = wave + r * 8;
      gload_lds16(Arow + (size_t)g * 8 * 512 + kt, S + buf * (64 * GRP) + g * GRP);
    }
  };
  auto STAGE_B = [&](int buf, int kt) {
#pragma unroll
    for (int r = 0; r < 4; ++r) {
      int g = wave + r * 8;
      gload_lds16(Brow + (size_t)g * 8 * 512 + kt, S + buf * (64 * GRP) + (32 + g) * GRP);
    }
  };
  STAGE_A(0, 0);
  STAGE_B(0, 0);
  asm volatile("s_waitcnt vmcnt(0)" ::: "memory");
  __builtin_amdgcn_s_barrier();
  const int nt = 512 / BK;
  for (int tt = 0; tt < nt; ++tt) {
    const int cur = tt & 1;
    const unsigned short* Sa = S + cur * (64 * GRP);
    const unsigned short* Sb = Sa + 32 * GRP;
    const bool pf = (tt + 1 < nt);
#pragma unroll
    for (int ks = 0; ks < 4; ++ks) {
      int qx = (ks * 2 + hi) ^ w7;
      bf16x8 a[2], bb[4];
#pragma unroll
      for (int i = 0; i < 2; ++i)
        a[i] = *(const bf16x8*)(Sa + ((wm >> 3) + i * 4 + g2) * GRP + w7 * 64 + qx * 8);
#pragma unroll
      for (int j = 0; j < 4; ++j)
        bb[j] = *(const bf16x8*)(Sb + ((wn >> 3) + j * 4 + g2) * GRP + w7 * 64 + qx * 8);
      if (pf && ks == 0) STAGE_A(cur ^ 1, (tt + 1) * BK);
      if (pf && ks == 1) STAGE_B(cur ^ 1, (tt + 1) * BK);
      __builtin_amdgcn_s_barrier();
      asm volatile("s_waitcnt lgkmcnt(0)" ::: "memory");
      __builtin_amdgcn_sched_barrier(0);
      __builtin_amdgcn_s_setprio(1);
#pragma unroll
      for (int i = 0; i < 2; ++i)
#pragma unroll
        for (int j = 0; j < 4; ++j)
          acc[i][j] = __builtin_amdgcn_mfma_f32_32x32x16_bf16(a[i], bb[j], acc[i][j], 0, 0, 0);
      __builtin_amdgcn_s_setprio(0);
      __builtin_amdgcn_sched_barrier(0);
      if (ks < 3) __builtin_amdgcn_s_barrier();
    }
    if (pf) asm volatile("s_waitcnt vmcnt(0)" ::: "memory");
    __builtin_amdgcn_s_barrier();
    asm volatile("" ::: "memory");
  }
  float bv[4], wv[4];
#pragma unroll
  for (int j = 0; j < 4; ++j) {
    int col = n0 + wn + j * 32 + l31;
    bv[j] = br[col]; wv[j] = w2[col];
  }
#pragma unroll
  for (int i = 0; i < 2; ++i) {
#pragma unroll
    for (int rg = 0; rg < 16; ++rg) {
      float s = 0.f;
#pragma unroll
      for (int j = 0; j < 4; ++j) {
        float v = acc[i][j][rg] + bv[j];   // residual folded into Wr+I
        v = v > 0.f ? v : 0.f;
        s += v * wv[j];
      }
      s += __shfl_xor(s, 1); s += __shfl_xor(s, 2); s += __shfl_xor(s, 4);
      s += __shfl_xor(s, 8); s += __shfl_xor(s, 16);
      if (l31 == 0) {
        int row = m0 + wm + i * 32 + (rg & 3) + 8 * (rg >> 2) + 4 * hi;
        atomicAdd(&so[row], s);
      }
    }
  }
}

// ---------- small kernels ----------
__global__ __launch_bounds__(256) void init_so_kernel(float* so, const float* b2) {
  int m = blockIdx.x * 256 + threadIdx.x;
  so[m] = b2[0];
}
__global__ __launch_bounds__(256) void update_kernel(float* std_cum, float* so,
                                                     const float* b2_next, int first) {
  int m = blockIdx.x * 256 + threadIdx.x;
  float s = so[m];
  if (!first) s += std_cum[m];
  std_cum[m] = s;
  so[m] = b2_next[0];
}
__global__ __launch_bounds__(256) void finalize_kernel(float* out, const float* std_cum,
                                                       const float* so) {
  int m = blockIdx.x * 256 + threadIdx.x;
  out[m] = std_cum[m] + so[m];
}

extern "C" void kernel_launch(void* const* d_in, const int* in_sizes, int n_in,
                              void* d_out, int out_size, void* d_ws, size_t ws_size,
                              hipStream_t stream) {
  const int B = 8, N = NPTS, M = B * N;
  const float* latent = (const float*)d_in[0];
  const float* rp = (const float*)d_in[1];
  const float* w1[3] = {(const float*)d_in[2], (const float*)d_in[8], (const float*)d_in[14]};
  const float* b1[3] = {(const float*)d_in[3], (const float*)d_in[9], (const float*)d_in[15]};
  const float* wr[3] = {(const float*)d_in[4], (const float*)d_in[10], (const float*)d_in[16]};
  const float* br[3] = {(const float*)d_in[5], (const float*)d_in[11], (const float*)d_in[17]};
  const float* w2[3] = {(const float*)d_in[6], (const float*)d_in[12], (const float*)d_in[18]};
  const float* b2[3] = {(const float*)d_in[7], (const float*)d_in[13], (const float*)d_in[19]};

  char* ws = (char*)d_ws;
  auto carve = [&](size_t bytes) {
    char* p = ws;
    ws += (bytes + 255) & ~(size_t)255;
    return p;
  };
  unsigned short* X  = (unsigned short*)carve((size_t)M * LDX * 2);
  unsigned short* H1 = (unsigned short*)carve((size_t)M * 512 * 2);
  unsigned short* W1t[3], *Wrt[3];
  for (int s = 0; s < 3; ++s) W1t[s] = (unsigned short*)carve((size_t)512 * LDX * 2);
  for (int s = 0; s < 3; ++s) Wrt[s] = (unsigned short*)carve((size_t)512 * 512 * 2);
  float* std_cum = (float*)carve((size_t)M * 4);
  float* so      = (float*)carve((size_t)M * 4);

  const size_t ldsBytes = (size_t)LDSU16 * 2;   // 133,120 B

  convw6_kernel<<<dim3(LDX / 32, 16, 6), 256, 0, stream>>>(
      w1[0], w1[1], w1[2], wr[0], wr[1], wr[2],
      W1t[0], W1t[1], W1t[2], Wrt[0], Wrt[1], Wrt[2]);
  conv_latent_kernel<<<(M * 128) / 256, 256, 0, stream>>>(latent, X);
  knn_kernel<<<dim3(N / 64, B), 512, 0, stream>>>(rp, X);
  init_so_kernel<<<M / 256, 256, 0, stream>>>(so, b2[0]);

  for (int s = 0; s < 3; ++s) {
    if (s == 0) {
      gemm_relu_kernel<<<dim3(512 / BN, M / BM), 512, ldsBytes, stream>>>(
          X, W1t[s], b1[s], H1, LDX, LDX, LDX, nullptr, nullptr);
    } else {
      gemm_relu_kernel<<<dim3(512 / BN, M / BM), 512, ldsBytes, stream>>>(
          X, W1t[s], b1[s], H1, 512, LDX, LDX, std_cum, w1[s] + (size_t)512 * 512);
    }
    gemm_res_kernel<<<dim3(512 / BN, M / BM), 512, ldsBytes, stream>>>(
        H1, Wrt[s], br[s], w2[s], so);
    if (s < 2)
      update_kernel<<<M / 256, 256, 0, stream>>>(std_cum, so, b2[s + 1], s == 0 ? 1 : 0);
  }
  finalize_kernel<<<M / 256, 256, 0, stream>>>((float*)d_out, std_cum, so);
}